// Round 14
// baseline (158.785 us; speedup 1.0000x reference)
//
#include <hip/hip_runtime.h>

namespace {

typedef __bf16 bf16x8 __attribute__((ext_vector_type(8)));
typedef float f32x4 __attribute__((ext_vector_type(4)));
typedef unsigned int uint4v __attribute__((ext_vector_type(4)));

#define MFMA16(a,b,c) __builtin_amdgcn_mfma_f32_16x16x32_bf16((a),(b),(c),0,0,0)

constexpr float SCALE = 0.125f;   // 1/sqrt(64)

// ---------------- ws layout ----------------
// slots i*8192, i=0..6: 0 embed, 1 M0T, 2 Wvo, 3 M1T, 4 Nw1, 5 M2T, 6 Nw2
// slots 0,1 (LDS-staged pre-BAR_A): pi-packed + XOR-swizzled rows (linear
//   global_load_lds copy yields the swizzled LDS tile). slots 2..6 + NV + HW
//   (direct-global reads): pi-packed plain row-major.
constexpr int WS_HW  = 57344;  // head weights [16][128] bf16, 4096 B
constexpr int WS_NV  = 61440;  // Nv tile [16][64] bf16 (rows 0-3 used), 2048 B
constexpr int WS_VEC = 63488;  // f32 vecs: m0,cc,wt1,wt2,d1,e1,d2,e2 (8 x 64)
constexpr int WS_SC  = 65536;  // f32 scalars: c1, hbk1, c2, hbk2

__device__ __forceinline__ int PI(int c){ return 4*(c&15) + (c>>4); }
__device__ __forceinline__ int PINV(int p){ return 16*(p&3) + (p>>2); }

__device__ __forceinline__ unsigned short f2b(float f){
  return __builtin_bit_cast(unsigned short, (__bf16)f);
}
__device__ __forceinline__ unsigned pack2(float a, float b){
  return (unsigned)f2b(a) | ((unsigned)f2b(b)<<16);
}
template<int ACT>  // 0 none, 1 leaky-relu(0.2), 2 tanh
__device__ __forceinline__ float actf(float v){
  if constexpr (ACT==1) return v>0.f ? v : 0.2f*v;
  else if constexpr (ACT==2) return 1.f - 2.f/(__expf(2.f*v)+1.f);
  else return v;
}

__device__ __forceinline__ void bar_lgkm(){
  asm volatile("s_waitcnt lgkmcnt(0)\n\ts_barrier" ::: "memory");
}
__device__ __forceinline__ void bar_full(){
  asm volatile("s_waitcnt vmcnt(0) lgkmcnt(0)\n\ts_barrier" ::: "memory");
}

// ---------------- prep kernel (proven, unchanged) ----------------
struct PrepP {
  const float *embed_w, *mean_w, *ls_w;
  const float *ia_wq, *ia_bq, *ia_wk, *ia_wv, *ia_wo, *ia_bv, *ia_bo;
  const float *c1_wq, *c1_bq, *c1_wk, *c1_bk, *c1_wv, *c1_bv, *c1_wo, *c1_bo;
  const float *c2_wq, *c2_bq, *c2_wk, *c2_bk, *c2_wv, *c2_bv, *c2_wo, *c2_bo;
  const float *msg_w, *msg_b, *st_w, *st_b;
  char* ws;
};

__device__ void mmAB_f32(const float* A, const float* B, float* O){
  const int t=threadIdx.x, r=t>>2, c0=(t&3)*16;
  float acc[16];
  #pragma unroll
  for(int j=0;j<16;j++) acc[j]=0.f;
  for(int h=0;h<64;h++){
    const float a=A[r*64+h];
    #pragma unroll
    for(int j=0;j<16;j++) acc[j]=fmaf(a,B[h*64+c0+j],acc[j]);
  }
  #pragma unroll
  for(int j=0;j<16;j++) O[r*64+c0+j]=acc[j];
}
__device__ void mmAB_bf(const float* A, const float* B, __bf16* D){
  const int t=threadIdx.x, r=t>>2, c0=(t&3)*16;
  float acc[16];
  #pragma unroll
  for(int j=0;j<16;j++) acc[j]=0.f;
  for(int h=0;h<64;h++){
    const float a=A[r*64+h];
    #pragma unroll
    for(int j=0;j<16;j++) acc[j]=fmaf(a,B[h*64+c0+j],acc[j]);
  }
  #pragma unroll
  for(int j=0;j<16;j++) D[r*64+PI(c0+j)]=(__bf16)acc[j];
}
__device__ void mmTA_bfx(const float* A, const float* B, __bf16* D){
  const int t=threadIdx.x, a=t>>2, b0=(t&3)*16;
  float acc[16];
  #pragma unroll
  for(int j=0;j<16;j++) acc[j]=0.f;
  for(int h=0;h<64;h++){
    const float av=A[h*64+a];
    #pragma unroll
    for(int j=0;j<16;j++) acc[j]=fmaf(av,B[h*64+b0+j],acc[j]);
  }
  #pragma unroll
  for(int j=0;j<16;j++) D[a*64 + (PI(b0+j) ^ ((a&7)<<3))]=(__bf16)acc[j];
}

__global__ void prep_kernel(PrepP q){
  __shared__ float PF[2][4096];
  __shared__ float hv[64], gv[64];
  const int job=blockIdx.x, t=threadIdx.x;
  char* ws=q.ws;
  float* VECF=(float*)(ws+WS_VEC);
  float* SCF =(float*)(ws+WS_SC);
  __bf16* NVD=(__bf16*)(ws+WS_NV);

  if(job==0){
    __bf16* emb=(__bf16*)(ws+0*8192);
    #pragma unroll
    for(int i=0;i<16;i++){
      const int idx=t*16+i, o=idx>>6, pp=idx&63;
      emb[idx]=(__bf16)q.embed_w[o*64 + PINV(pp ^ ((o&7)<<3))];
    }
    __bf16* hw=(__bf16*)(ws+WS_HW);
    #pragma unroll
    for(int i=0;i<8;i++){
      const int flat=t*8+i, o=flat>>7, qq=flat&127, half=qq>>6, pp=qq&63;
      const float v=(o<8)?q.mean_w[o*128+half*64+PINV(pp)]
                         :q.ls_w[(o-8)*128+half*64+PINV(pp)];
      hw[flat]=(__bf16)v;
    }
    #pragma unroll
    for(int i=0;i<3;i++){ const int id=t*3+i; if(id<768) NVD[256+id]=(__bf16)0.f; }
  } else if(job==1){
    // M0T staged (pi + XOR for linear global_load_lds)
    mmTA_bfx(q.ia_wk, q.ia_wq, (__bf16*)(ws+1*8192));
    if(t<64){ float s=0; for(int h=0;h<64;h++) s+=q.ia_wk[h*64+t]*q.ia_bq[h]; VECF[t]=s; }
  } else if(job==2){
    mmAB_bf(q.ia_wo, q.ia_wv, (__bf16*)(ws+2*8192));    // Wvo (direct)
    if(t<64){ float s=q.ia_bo[t]; for(int h=0;h<64;h++) s+=q.ia_wo[t*64+h]*q.ia_bv[h];
              VECF[64+t]=s; }
  } else if(job==3 || job==5){
    const int cons=(job==3)?0:1;
    const float *wq=cons?q.c2_wq:q.c1_wq, *bq=cons?q.c2_bq:q.c1_bq;
    const float *wk=cons?q.c2_wk:q.c1_wk, *bk=cons?q.c2_bk:q.c1_bk;
    mmAB_f32(wq, q.st_w, PF[0]);                       // G = wq@st_w
    if(t<64){ float s=bq[t]; for(int k=0;k<64;k++) s+=wq[t*64+k]*q.st_b[k]; hv[t]=s; }
    __syncthreads();
    mmAB_f32(wk, q.msg_w, PF[1]);                      // F = wk@msg_w
    if(t<64){ float s=0; for(int k=0;k<64;k++) s+=wk[t*64+k]*q.msg_b[k]; gv[t]=s; }
    __syncthreads();
    // M1T/M2T now DIRECT-global (plain pi, no XOR)
    { const int a=t>>2, b0=(t&3)*16;
      float acc[16];
      #pragma unroll
      for(int j=0;j<16;j++) acc[j]=0.f;
      for(int h=0;h<64;h++){
        const float av=PF[1][h*64+a];
        #pragma unroll
        for(int j=0;j<16;j++) acc[j]=fmaf(av,PF[0][h*64+b0+j],acc[j]);
      }
      __bf16* D=(__bf16*)(ws+(cons?5:3)*8192);
      #pragma unroll
      for(int j=0;j<16;j++) D[a*64+PI(b0+j)]=(__bf16)acc[j];
    }
    if(t<64){
      float s=0; for(int h=0;h<64;h++) s+=PF[1][h*64+t]*hv[h];
      VECF[128+cons*64+t]=s;                            // wt = F^T h
      float s0=0,s1=0;
      for(int h=0;h<64;h++){ s0+=PF[0][h*64+t]*gv[h]; s1+=PF[0][h*64+t]*bk[h]; }
      NVD[(2*cons  )*64+PI(t)]=(__bf16)s0;              // u-vec  = G^T g
      NVD[(2*cons+1)*64+PI(t)]=(__bf16)s1;              // qb-vec = G^T bk
    }
    if(t==0){
      float c=0,hb=0;
      for(int i=0;i<64;i++){ c+=hv[i]*gv[i]; hb+=hv[i]*bk[i]; }
      SCF[2*cons]=c; SCF[2*cons+1]=hb;
    }
  } else {
    const int cons=(job==4)?0:1;
    const float *wo=cons?q.c2_wo:q.c1_wo, *wvv=cons?q.c2_wv:q.c1_wv;
    const float *bv=cons?q.c2_bv:q.c1_bv, *bo=cons?q.c2_bo:q.c1_bo;
    mmAB_f32(wo, wvv, PF[0]);                          // U = wo@wv
    if(t<64){ float s=bo[t]; for(int h=0;h<64;h++) s+=wo[t*64+h]*bv[h];
              VECF[320+cons*128+t]=s; }                 // e = wo@bv + bo
    __syncthreads();
    mmAB_bf(PF[0], q.msg_w, (__bf16*)(ws+(cons?6:4)*8192));  // Nw (direct)
    if(t<64){ float s=0; for(int k=0;k<64;k++) s+=PF[0][t*64+k]*q.msg_b[k];
              VECF[256+cons*128+t]=s; }                 // d = U@msg_b
  }
}

// ---------------- main kernel ----------------
struct Params {
  const float *x, *rnd; const int *idx;
  const float *embed_b, *mean_b, *ls_b;
  const char* ws; float* out; int std_off;
};

__device__ __forceinline__ bf16x8 fragld(const char* buf, int row, int kb){
  const int byte = row*128 + (kb ^ ((row&7)<<4));
  return __builtin_bit_cast(bf16x8, *reinterpret_cast<const uint4v*>(buf + byte));
}
__device__ __forceinline__ bf16x8 gld(const char* a){
  return __builtin_bit_cast(bf16x8, *reinterpret_cast<const uint4v*>(a));
}
__device__ __forceinline__ void stageT(const char* src, char* L, int t){
  __builtin_amdgcn_global_load_lds(
      (const __attribute__((address_space(1))) unsigned int*)(src + t*16),
      (__attribute__((address_space(3))) unsigned int*)(L + (t>>6)*1024), 16, 0, 0);
}
__device__ __forceinline__ void loadB_lds(const char* Bl, bf16x8* bf, int fr, int fg){
  #pragma unroll
  for(int n=0;n<4;n++){
    bf[2*n]   = fragld(Bl, n*16+fr, fg*16);
    bf[2*n+1] = fragld(Bl, n*16+fr, 64+fg*16);
  }
}
__device__ __forceinline__ void loadB_gl(const char* W, bf16x8* bf, int fr, int fg){
  #pragma unroll
  for(int n=0;n<4;n++){
    bf[2*n]   = gld(W + (n*16+fr)*128 + fg*16);
    bf[2*n+1] = gld(W + (n*16+fr)*128 + 64 + fg*16);
  }
}

// acc += A(lds own rows) @ B(lds full tile)
__device__ __forceinline__ void mm_AB(const char* A, const char* Bl, f32x4* acc,
                                      int fr,int fg,int wv4){
  const bf16x8 a0=fragld(A,16*wv4+fr,fg*16), a1=fragld(A,16*wv4+fr,64+fg*16);
  #pragma unroll
  for(int n=0;n<4;n++){
    acc[n]=MFMA16(a0, fragld(Bl,n*16+fr,fg*16),    acc[n]);
    acc[n]=MFMA16(a1, fragld(Bl,n*16+fr,64+fg*16), acc[n]);
  }
}
// acc += A(lds own rows) @ B(preloaded frag regs)
__device__ __forceinline__ void mm_ABr(const char* A, const bf16x8* bf, f32x4* acc,
                                       int fr,int fg,int wv4){
  const bf16x8 a0=fragld(A,16*wv4+fr,fg*16), a1=fragld(A,16*wv4+fr,64+fg*16);
  #pragma unroll
  for(int n=0;n<4;n++){
    acc[n]=MFMA16(a0, bf[2*n],   acc[n]);
    acc[n]=MFMA16(a1, bf[2*n+1], acc[n]);
  }
}
// acc += A(regs 2 frags) @ B(preloaded frag regs)
__device__ __forceinline__ void mm_rAB(bf16x8 a0, bf16x8 a1, const bf16x8* bf,
                                       f32x4* acc){
  #pragma unroll
  for(int n=0;n<4;n++){
    acc[n]=MFMA16(a0, bf[2*n],   acc[n]);
    acc[n]=MFMA16(a1, bf[2*n+1], acc[n]);
  }
}

template<int ACT>
__device__ __forceinline__ void store_cb(char* C, const f32x4* acc, const float* bz,
                                         int fr,int fg,int wv4){
  #pragma unroll
  for(int r=0;r<4;r++){
    const int R=16*wv4+4*fg+r;
    float v[4];
    #pragma unroll
    for(int n=0;n<4;n++) v[n]=actf<ACT>(acc[n][r]+bz[n]);
    uint2 pk; pk.x=pack2(v[0],v[1]); pk.y=pack2(v[2],v[3]);
    *reinterpret_cast<uint2*>(C + R*128 + ((8*fr)^((R&7)<<4))) = pk;
  }
}
__device__ __forceinline__ void store_rb(char* C, const f32x4* acc, const float* dR,
                                         int fr,int fg,int wv4){
  #pragma unroll
  for(int r=0;r<4;r++){
    const int R=16*wv4+4*fg+r;
    float v[4];
    #pragma unroll
    for(int n=0;n<4;n++) v[n]=acc[n][r]+dR[r];
    uint2 pk; pk.x=pack2(v[0],v[1]); pk.y=pack2(v[2],v[3]);
    *reinterpret_cast<uint2*>(C + R*128 + ((8*fr)^((R&7)<<4))) = pk;
  }
}

// Softmax with PRELOADED B-frags, NO max-subtraction (|s*SCALE| bounded ~8;
// exp safe in f32; ratio-identical). MODE 0 plain, 1 mg, 2 1-mg.
template<int MODE>
__device__ __forceinline__ void ssoft(const char* Aq, const bf16x8* bf, char* P,
                                      const float* rs, const float* as_,
                                      const float* zu, const float* zq,
                                      float cu, float cq,
                                      int fr,int fg,int wv4){
  f32x4 acc[4];
  #pragma unroll
  for(int n=0;n<4;n++) acc[n]=f32x4{0.f,0.f,0.f,0.f};
  const bf16x8 a0=fragld(Aq,16*wv4+fr,fg*16), a1=fragld(Aq,16*wv4+fr,64+fg*16);
  #pragma unroll
  for(int n=0;n<4;n++){
    acc[n]=MFMA16(a0, bf[2*n],   acc[n]);
    acc[n]=MFMA16(a1, bf[2*n+1], acc[n]);
  }
  unsigned mbits=0;
  if constexpr(MODE!=0){
    float rc[4], aR[4], ucR[4], qtR[4]; bool giR[4];
    #pragma unroll
    for(int n=0;n<4;n++) rc[n]=rs[n*16+fr];
    #pragma unroll
    for(int r=0;r<4;r++){
      const int R=16*wv4+4*fg+r;
      aR[r]=as_[R]; giR[r]=rs[R]>aR[r];
      ucR[r]=zu[R]+cu; qtR[r]=zq[R]+cq;
    }
    #pragma unroll
    for(int n=0;n<4;n++){
      #pragma unroll
      for(int r=0;r<4;r++){
        bool mv=giR[r]||(rc[n]>aR[r]);
        if constexpr(MODE==2) mv=!mv;
        const float mf=mv?1.f:0.f;
        if(mv) mbits|=1u<<(n*4+r);
        acc[n][r]=(mf*(acc[n][r]+ucR[r])+qtR[r])*SCALE;
      }
    }
  }
  float sm[4]={0,0,0,0};
  #pragma unroll
  for(int n=0;n<4;n++){
    #pragma unroll
    for(int r=0;r<4;r++){
      float e;
      if constexpr(MODE==0) e=__expf(acc[n][r]*SCALE);
      else e=__expf(acc[n][r]);
      acc[n][r]=e; sm[r]+=e;
    }
  }
  #pragma unroll
  for(int m=1;m<16;m<<=1){
    #pragma unroll
    for(int r=0;r<4;r++) sm[r]+=__shfl_xor(sm[r],m);
  }
  #pragma unroll
  for(int r=0;r<4;r++){
    const int R=16*wv4+4*fg+r;
    const float ri=1.f/sm[r];
    float v[4];
    #pragma unroll
    for(int n=0;n<4;n++){
      float e=acc[n][r]*ri;
      if constexpr(MODE!=0) e=(mbits&(1u<<(n*4+r)))?e:0.f;
      v[n]=e;
    }
    uint2 pk; pk.x=pack2(v[0],v[1]); pk.y=pack2(v[2],v[3]);
    *reinterpret_cast<uint2*>(P + R*128 + ((8*fr)^((R&7)<<4))) = pk;
  }
}

__global__ __launch_bounds__(512,6) void rap_kernel(Params p, int Bb){
  __shared__ __align__(16) char Bact[2][3][8192];   // per-item tiles (A2 doubles as
                                                    // embed/M0 staging pre-S4)
  __shared__ float rnd_s[2][64], a_s[2][64], zbuf[2][4][64];
  const int t=threadIdx.x;
  const int fr=t&15, fg=(t>>4)&3, wv=t>>6, l=t&63;
  const int item=wv>>2, wv4=wv&3;
  const int b0=blockIdx.x*2;
  const int bi=(b0+item<Bb)?(b0+item):(Bb-1);
  const char* ws=p.ws;
  const float* VECF=(const float*)(ws+WS_VEC);
  const float* SCF =(const float*)(ws+WS_SC);
  char* A0=Bact[item][0]; char* A1=Bact[item][1]; char* A2=Bact[item][2];
  bf16x8 bfv[8];

  // stage embed -> Bact[0][2], M0 -> Bact[1][2] (A2 tiles free until S4)
  stageT(ws+0*8192, Bact[0][2], t);
  stageT(ws+1*8192, Bact[1][2], t);
  if(t<128){
    const int it2=t>>6, i2=t&63;
    const int bb=(b0+it2<Bb)?(b0+it2):(Bb-1);
    rnd_s[it2][i2]=p.rnd[bb*64+i2];
    a_s[it2][i2]  =p.rnd[bb*64+p.idx[bb*64+i2]];
  }
  // stage x (own 16 rows) -> A0, pi+XOR packed, b128 stores
  {
    const float* Gx=p.x+(size_t)bi*4096;
    #pragma unroll
    for(int j=0;j<2;j++){
      const int lf=j*64+l, R=16*wv4+(lf>>3), k=lf&7;
      const float2 L0=*reinterpret_cast<const float2*>(Gx+R*64+2*k);
      const float2 L1=*reinterpret_cast<const float2*>(Gx+R*64+16+2*k);
      const float2 L2=*reinterpret_cast<const float2*>(Gx+R*64+32+2*k);
      const float2 L3=*reinterpret_cast<const float2*>(Gx+R*64+48+2*k);
      uint4 pk;
      pk.x=pack2(L0.x,L1.x); pk.y=pack2(L2.x,L3.x);
      pk.z=pack2(L0.y,L1.y); pk.w=pack2(L2.y,L3.y);
      *reinterpret_cast<uint4*>(A0 + R*128 + ((16*k)^((R&7)<<4)))=pk;
    }
  }
  bar_full();                                        // BAR_A: x + embed/M0 stageT
  // S1: E = lrelu(x@embed^T + eb) -> A1 (own rows); B = Bact[0][2] (staged embed)
  { f32x4 acc[4]={{0,0,0,0},{0,0,0,0},{0,0,0,0},{0,0,0,0}};
    mm_AB(A0, Bact[0][2], acc, fr,fg,wv4);
    float bz[4];
    #pragma unroll
    for(int n=0;n<4;n++) bz[n]=p.embed_b[n*16+fr];
    store_cb<1>(A1, acc, bz, fr,fg,wv4); }
  // S2: T0' = E@M0 + m0 -> A0 (own rows); B = Bact[1][2] (staged M0)
  { f32x4 acc[4]={{0,0,0,0},{0,0,0,0},{0,0,0,0},{0,0,0,0}};
    mm_AB(A1, Bact[1][2], acc, fr,fg,wv4);
    float bz[4];
    #pragma unroll
    for(int n=0;n<4;n++) bz[n]=VECF[n*16+fr];
    store_cb<0>(A0, acc, bz, fr,fg,wv4); }
  bar_lgkm();                                        // BAR1: E/T0' full; embed/M0 dead
  // prefetch Wvo A-frags
  const bf16x8 aVo0=gld(ws+2*8192+(16*wv4+fr)*128+fg*16);
  const bf16x8 aVo1=gld(ws+2*8192+(16*wv4+fr)*128+64+fg*16);
  // S3+S4 share B = E (A1)
  loadB_lds(A1, bfv, fr, fg);
  // S3: P = softmax(T0'@E^T * SCALE) in-place A0
  ssoft<0>(A0, bfv, A0, nullptr,nullptr,nullptr,nullptr,0.f,0.f, fr,fg,wv4);
  // S4: VOT = Wvo@E^T -> A2 (own rows; embed/M0 staging dead since BAR1)
  { f32x4 acc[4]={{0,0,0,0},{0,0,0,0},{0,0,0,0},{0,0,0,0}};
    mm_rAB(aVo0, aVo1, bfv, acc);
    const float bz[4]={0,0,0,0};
    store_cb<0>(A2, acc, bz, fr,fg,wv4); }
  bar_lgkm();                                        // BAR2: VOT full (E dead)
  // prefetch Nv frags; hoist M1 B-frags (JIT global, consumed S6, covered by S5)
  const bf16x8 nv0=gld(ws+WS_NV+fr*128+fg*16);
  const bf16x8 nv1=gld(ws+WS_NV+fr*128+64+fg*16);
  loadB_gl(ws+3*8192, bfv, fr, fg);                  // M1
  // S5: ATT = tanh(P@VOT + cc) -> A1 (own rows)
  { f32x4 acc[4]={{0,0,0,0},{0,0,0,0},{0,0,0,0},{0,0,0,0}};
    mm_AB(A0, A2, acc, fr,fg,wv4);
    float bz[4];
    #pragma unroll
    for(int n=0;n<4;n++) bz[n]=VECF[64+n*16+fr];
    store_cb<2>(A1, acc, bz, fr,fg,wv4); }
  // S6: T1' = ATT@M1 + wt1 -> A0 ; Z = ATT@Nv -> zbuf (own rows)
  { const bf16x8 a0=fragld(A1,16*wv4+fr,fg*16), a1=fragld(A1,16*wv4+fr,64+fg*16);
    f32x4 acc[4]={{0,0,0,0},{0,0,0,0},{0,0,0,0},{0,0,0,0}};
    #pragma unroll
    for(int n=0;n<4;n++){
      acc[n]=MFMA16(a0, bfv[2*n],   acc[n]);
      acc[n]=MFMA16(a1, bfv[2*n+1], acc[n]);
    }
    f32x4 za={0,0,0,0};
    za=MFMA16(a0, nv0, za);
    za=MFMA16(a1, nv1, za);
    if(fr<4){
      #pragma unroll
      for(int r=0;r<4;r++) zbuf[item][fr][16*wv4+4*fg+r]=za[r];
    }
    float bz[4];
    #pragma unroll
    for(int n=0;n<4;n++) bz[n]=VECF[128+n*16+fr];
    store_cb<0>(A0, acc, bz, fr,fg,wv4); }
  bar_lgkm();                                        // BAR3: ATT + T1' + zbuf full
  // prefetch Nw1 A-frags
  const bf16x8 aN10=gld(ws+4*8192+(16*wv4+fr)*128+fg*16);
  const bf16x8 aN11=gld(ws+4*8192+(16*wv4+fr)*128+64+fg*16);
  // S7+S7b share B = ATT (A1)
  loadB_lds(A1, bfv, fr, fg);
  ssoft<1>(A0, bfv, A0, rnd_s[item], a_s[item], zbuf[item][0], zbuf[item][1],
           SCF[0], SCF[1], fr,fg,wv4);               // P1 -> A0
  { f32x4 acc[4]={{0,0,0,0},{0,0,0,0},{0,0,0,0},{0,0,0,0}};
    mm_rAB(aN10, aN11, bfv, acc);
    float dR[4];
    #pragma unroll
    for(int r=0;r<4;r++) dR[r]=VECF[256+16*wv4+4*fg+r];
    store_rb(A2, acc, dR, fr,fg,wv4); }              // VMO1T (+d1) -> A2
  bar_lgkm();                                        // BAR4: VMO1T + P1 full
  // hoist M2 B-frags (consumed S8b, covered by S8a); prefetch head frags 0-63
  loadB_gl(ws+5*8192, bfv, fr, fg);                  // M2
  const bf16x8 h0=gld(ws+WS_HW + fr*256 + 0*64 + fg*16);
  const bf16x8 h1=gld(ws+WS_HW + fr*256 + 1*64 + fg*16);
  f32x4 hacc={0,0,0,0};
  // S8a: o1acc = P1@VMO1T; park O1 = lrelu(+e1) -> A0 own rows; fold heads
  { f32x4 o1acc[4]={{0,0,0,0},{0,0,0,0},{0,0,0,0},{0,0,0,0}};
    mm_AB(A0, A2, o1acc, fr,fg,wv4);
    float bz[4];
    #pragma unroll
    for(int n=0;n<4;n++) bz[n]=VECF[320+n*16+fr];
    store_cb<1>(A0, o1acc, bz, fr,fg,wv4); }
  hacc=MFMA16(fragld(A0,16*wv4+fr,fg*16),    h0, hacc);
  hacc=MFMA16(fragld(A0,16*wv4+fr,64+fg*16), h1, hacc);
  // S8b: T2' = ATT@M2 + wt2 -> A0 (own rows; O1 consumed)
  { f32x4 acc[4]={{0,0,0,0},{0,0,0,0},{0,0,0,0},{0,0,0,0}};
    mm_ABr(A1, bfv, acc, fr,fg,wv4);
    float bz[4];
    #pragma unroll
    for(int n=0;n<4;n++) bz[n]=VECF[192+n*16+fr];
    store_cb<0>(A0, acc, bz, fr,fg,wv4); }
  bar_lgkm();                                        // BAR5: A2 reads done; T2' full
  // prefetch Nw2 A-frags; reload ATT B-frags
  const bf16x8 aN20=gld(ws+6*8192+(16*wv4+fr)*128+fg*16);
  const bf16x8 aN21=gld(ws+6*8192+(16*wv4+fr)*128+64+fg*16);
  loadB_lds(A1, bfv, fr, fg);
  // S9: P2 = cons-softmax(T2'@ATT^T, inv) -> A0 ; S9b: VMO2T = Nw2@ATT^T + d2 -> A2
  ssoft<2>(A0, bfv, A0, rnd_s[item], a_s[item], zbuf[item][2], zbuf[item][3],
           SCF[2], SCF[3], fr,fg,wv4);
  { f32x4 acc[4]={{0,0,0,0},{0,0,0,0},{0,0,0,0},{0,0,0,0}};
    mm_rAB(aN20, aN21, bfv, acc);
    float dR[4];
    #pragma unroll
    for(int r=0;r<4;r++) dR[r]=VECF[384+16*wv4+4*fg+r];
    store_rb(A2, acc, dR, fr,fg,wv4); }
  bar_lgkm();                                        // BAR6: VMO2T + P2 full (ATT dead)
  // prefetch head frags 64-127
  const bf16x8 h2=gld(ws+WS_HW + fr*256 + 2*64 + fg*16);
  const bf16x8 h3=gld(ws+WS_HW + fr*256 + 3*64 + fg*16);
  // S10: o2acc = P2@VMO2T; park O2 = lrelu(+e2) -> A1 own rows; fold heads
  { f32x4 acc[4]={{0,0,0,0},{0,0,0,0},{0,0,0,0},{0,0,0,0}};
    mm_AB(A0, A2, acc, fr,fg,wv4);
    float bz[4];
    #pragma unroll
    for(int n=0;n<4;n++) bz[n]=VECF[448+n*16+fr];
    store_cb<1>(A1, acc, bz, fr,fg,wv4); }
  hacc=MFMA16(fragld(A1,16*wv4+fr,fg*16),    h2, hacc);
  hacc=MFMA16(fragld(A1,16*wv4+fr,64+fg*16), h3, hacc);
  // out: row R = agent (own), col fr = out-dim
  if(b0+item<Bb){
    const float bz=(fr<8)?p.mean_b[fr]:p.ls_b[fr-8];
    #pragma unroll
    for(int r=0;r<4;r++){
      const int R=16*wv4+4*fg+r;
      const int g=((b0+item)*64+R)*8;
      float v=hacc[r]+bz;
      if(fr<8) p.out[g+fr]=v;
      else{ v=fminf(fmaxf(v,-20.f),2.f); p.out[p.std_off+g+(fr-8)]=__expf(v); }
    }
  }
}

} // namespace

extern "C" void kernel_launch(void* const* d_in, const int* in_sizes, int n_in,
                              void* d_out, int out_size, void* d_ws, size_t ws_size,
                              hipStream_t stream){
  (void)n_in; (void)out_size; (void)ws_size;
  PrepP q;
  q.embed_w=(const float*)d_in[3];
  q.ia_wq=(const float*)d_in[5];  q.ia_bq=(const float*)d_in[6];
  q.ia_wk=(const float*)d_in[7];
  q.ia_wv=(const float*)d_in[9];  q.ia_bv=(const float*)d_in[10];
  q.ia_wo=(const float*)d_in[11]; q.ia_bo=(const float*)d_in[12];
  q.c1_wq=(const float*)d_in[13]; q.c1_bq=(const float*)d_in[14];
  q.c1_wk=(const float*)d_in[15]; q.c1_bk=(const float*)d_in[16];
  q.c1_wv=(const float*)d_in[17]; q.c1_bv=(const float*)d_in[18];
  q.c1_wo=(const float*)d_in[19]; q.c1_bo=(const float*)d_in[20];
  q.c2_wq=(const float*)d_in[21]; q.c2_bq=(const float*)d_in[22];
  q.c2_wk=(const float*)d_in[23]; q.c2_bk=(const float*)d_in[24];
  q.c2_wv=(const float*)d_in[25]; q.c2_bv=(const float*)d_in[26];
  q.c2_wo=(const float*)d_in[27]; q.c2_bo=(const float*)d_in[28];
  q.msg_w=(const float*)d_in[29]; q.msg_b=(const float*)d_in[30];
  q.st_w =(const float*)d_in[31]; q.st_b =(const float*)d_in[32];
  q.mean_w=(const float*)d_in[33]; q.ls_w=(const float*)d_in[35];
  q.ws=(char*)d_ws;
  prep_kernel<<<dim3(7), dim3(256), 0, stream>>>(q);

  Params p;
  p.x  =(const float*)d_in[0];
  p.rnd=(const float*)d_in[1];
  p.idx=(const int*)  d_in[2];
  p.embed_b=(const float*)d_in[4];
  p.mean_b =(const float*)d_in[34];
  p.ls_b   =(const float*)d_in[36];
  p.ws=(const char*)d_ws;
  p.out=(float*)d_out;
  const int Bb=in_sizes[0]/4096;   // x is [B,64,64]
  p.std_off=Bb*64*8;
  const int nb=(Bb+1)/2;
  rap_kernel<<<dim3(nb), dim3(512), 0, stream>>>(p, Bb);
}

// Round 15
// 133.164 us; speedup vs baseline: 1.1924x; 1.1924x over previous
//
#include <hip/hip_runtime.h>

namespace {

typedef __bf16 bf16x8 __attribute__((ext_vector_type(8)));
typedef float f32x4 __attribute__((ext_vector_type(4)));
typedef unsigned int uint4v __attribute__((ext_vector_type(4)));

#define MFMA16(a,b,c) __builtin_amdgcn_mfma_f32_16x16x32_bf16((a),(b),(c),0,0,0)

constexpr float SCALE = 0.125f;   // 1/sqrt(64)

// ---------------- ws layout ----------------
// slots i*8192, i=0..6: 0 embed, 1 M0T, 2 Wvo, 3 M1T, 4 Nw1, 5 M2T, 6 Nw2
// slots 0,1 (LDS-staged pre-BAR_A): pi-packed + XOR-swizzled rows. slots 2..6 +
// NV + HW (direct-global reads): pi-packed plain row-major.
constexpr int WS_HW  = 57344;  // head weights [16][128] bf16, 4096 B
constexpr int WS_NV  = 61440;  // Nv tile [16][64] bf16 (rows 0-3 used), 2048 B
constexpr int WS_VEC = 63488;  // f32 vecs: m0,cc,wt1,wt2,d1,e1,d2,e2 (8 x 64)
constexpr int WS_SC  = 65536;  // f32 scalars: c1, hbk1, c2, hbk2

__device__ __forceinline__ int PI(int c){ return 4*(c&15) + (c>>4); }
__device__ __forceinline__ int PINV(int p){ return 16*(p&3) + (p>>2); }

__device__ __forceinline__ unsigned short f2b(float f){
  return __builtin_bit_cast(unsigned short, (__bf16)f);
}
__device__ __forceinline__ unsigned pack2(float a, float b){
  return (unsigned)f2b(a) | ((unsigned)f2b(b)<<16);
}
template<int ACT>  // 0 none, 1 leaky-relu(0.2), 2 tanh
__device__ __forceinline__ float actf(float v){
  if constexpr (ACT==1) return v>0.f ? v : 0.2f*v;
  else if constexpr (ACT==2) return 1.f - 2.f/(__expf(2.f*v)+1.f);
  else return v;
}

__device__ __forceinline__ void bar_lgkm(){
  asm volatile("s_waitcnt lgkmcnt(0)\n\ts_barrier" ::: "memory");
}
__device__ __forceinline__ void bar_full(){
  asm volatile("s_waitcnt vmcnt(0) lgkmcnt(0)\n\ts_barrier" ::: "memory");
}

// ---------------- prep kernel (R14 version) ----------------
struct PrepP {
  const float *embed_w, *mean_w, *ls_w;
  const float *ia_wq, *ia_bq, *ia_wk, *ia_wv, *ia_wo, *ia_bv, *ia_bo;
  const float *c1_wq, *c1_bq, *c1_wk, *c1_bk, *c1_wv, *c1_bv, *c1_wo, *c1_bo;
  const float *c2_wq, *c2_bq, *c2_wk, *c2_bk, *c2_wv, *c2_bv, *c2_wo, *c2_bo;
  const float *msg_w, *msg_b, *st_w, *st_b;
  char* ws;
};

__device__ void mmAB_f32(const float* A, const float* B, float* O){
  const int t=threadIdx.x, r=t>>2, c0=(t&3)*16;
  float acc[16];
  #pragma unroll
  for(int j=0;j<16;j++) acc[j]=0.f;
  for(int h=0;h<64;h++){
    const float a=A[r*64+h];
    #pragma unroll
    for(int j=0;j<16;j++) acc[j]=fmaf(a,B[h*64+c0+j],acc[j]);
  }
  #pragma unroll
  for(int j=0;j<16;j++) O[r*64+c0+j]=acc[j];
}
__device__ void mmAB_bf(const float* A, const float* B, __bf16* D){
  const int t=threadIdx.x, r=t>>2, c0=(t&3)*16;
  float acc[16];
  #pragma unroll
  for(int j=0;j<16;j++) acc[j]=0.f;
  for(int h=0;h<64;h++){
    const float a=A[r*64+h];
    #pragma unroll
    for(int j=0;j<16;j++) acc[j]=fmaf(a,B[h*64+c0+j],acc[j]);
  }
  #pragma unroll
  for(int j=0;j<16;j++) D[r*64+PI(c0+j)]=(__bf16)acc[j];
}
__device__ void mmTA_bfx(const float* A, const float* B, __bf16* D){
  const int t=threadIdx.x, a=t>>2, b0=(t&3)*16;
  float acc[16];
  #pragma unroll
  for(int j=0;j<16;j++) acc[j]=0.f;
  for(int h=0;h<64;h++){
    const float av=A[h*64+a];
    #pragma unroll
    for(int j=0;j<16;j++) acc[j]=fmaf(av,B[h*64+b0+j],acc[j]);
  }
  #pragma unroll
  for(int j=0;j<16;j++) D[a*64 + (PI(b0+j) ^ ((a&7)<<3))]=(__bf16)acc[j];
}

__global__ void prep_kernel(PrepP q){
  __shared__ float PF[2][4096];
  __shared__ float hv[64], gv[64];
  const int job=blockIdx.x, t=threadIdx.x;
  char* ws=q.ws;
  float* VECF=(float*)(ws+WS_VEC);
  float* SCF =(float*)(ws+WS_SC);
  __bf16* NVD=(__bf16*)(ws+WS_NV);

  if(job==0){
    __bf16* emb=(__bf16*)(ws+0*8192);
    #pragma unroll
    for(int i=0;i<16;i++){
      const int idx=t*16+i, o=idx>>6, pp=idx&63;
      emb[idx]=(__bf16)q.embed_w[o*64 + PINV(pp ^ ((o&7)<<3))];
    }
    __bf16* hw=(__bf16*)(ws+WS_HW);
    #pragma unroll
    for(int i=0;i<8;i++){
      const int flat=t*8+i, o=flat>>7, qq=flat&127, half=qq>>6, pp=qq&63;
      const float v=(o<8)?q.mean_w[o*128+half*64+PINV(pp)]
                         :q.ls_w[(o-8)*128+half*64+PINV(pp)];
      hw[flat]=(__bf16)v;
    }
    #pragma unroll
    for(int i=0;i<3;i++){ const int id=t*3+i; if(id<768) NVD[256+id]=(__bf16)0.f; }
  } else if(job==1){
    mmTA_bfx(q.ia_wk, q.ia_wq, (__bf16*)(ws+1*8192));   // M0T (staged)
    if(t<64){ float s=0; for(int h=0;h<64;h++) s+=q.ia_wk[h*64+t]*q.ia_bq[h]; VECF[t]=s; }
  } else if(job==2){
    mmAB_bf(q.ia_wo, q.ia_wv, (__bf16*)(ws+2*8192));    // Wvo (direct)
    if(t<64){ float s=q.ia_bo[t]; for(int h=0;h<64;h++) s+=q.ia_wo[t*64+h]*q.ia_bv[h];
              VECF[64+t]=s; }
  } else if(job==3 || job==5){
    const int cons=(job==3)?0:1;
    const float *wq=cons?q.c2_wq:q.c1_wq, *bq=cons?q.c2_bq:q.c1_bq;
    const float *wk=cons?q.c2_wk:q.c1_wk, *bk=cons?q.c2_bk:q.c1_bk;
    mmAB_f32(wq, q.st_w, PF[0]);                       // G = wq@st_w
    if(t<64){ float s=bq[t]; for(int k=0;k<64;k++) s+=wq[t*64+k]*q.st_b[k]; hv[t]=s; }
    __syncthreads();
    mmAB_f32(wk, q.msg_w, PF[1]);                      // F = wk@msg_w
    if(t<64){ float s=0; for(int k=0;k<64;k++) s+=wk[t*64+k]*q.msg_b[k]; gv[t]=s; }
    __syncthreads();
    // M1T/M2T direct-global (plain pi, no XOR)
    { const int a=t>>2, b0=(t&3)*16;
      float acc[16];
      #pragma unroll
      for(int j=0;j<16;j++) acc[j]=0.f;
      for(int h=0;h<64;h++){
        const float av=PF[1][h*64+a];
        #pragma unroll
        for(int j=0;j<16;j++) acc[j]=fmaf(av,PF[0][h*64+b0+j],acc[j]);
      }
      __bf16* D=(__bf16*)(ws+(cons?5:3)*8192);
      #pragma unroll
      for(int j=0;j<16;j++) D[a*64+PI(b0+j)]=(__bf16)acc[j];
    }
    if(t<64){
      float s=0; for(int h=0;h<64;h++) s+=PF[1][h*64+t]*hv[h];
      VECF[128+cons*64+t]=s;                            // wt = F^T h
      float s0=0,s1=0;
      for(int h=0;h<64;h++){ s0+=PF[0][h*64+t]*gv[h]; s1+=PF[0][h*64+t]*bk[h]; }
      NVD[(2*cons  )*64+PI(t)]=(__bf16)s0;              // u-vec  = G^T g
      NVD[(2*cons+1)*64+PI(t)]=(__bf16)s1;              // qb-vec = G^T bk
    }
    if(t==0){
      float c=0,hb=0;
      for(int i=0;i<64;i++){ c+=hv[i]*gv[i]; hb+=hv[i]*bk[i]; }
      SCF[2*cons]=c; SCF[2*cons+1]=hb;
    }
  } else {
    const int cons=(job==4)?0:1;
    const float *wo=cons?q.c2_wo:q.c1_wo, *wvv=cons?q.c2_wv:q.c1_wv;
    const float *bv=cons?q.c2_bv:q.c1_bv, *bo=cons?q.c2_bo:q.c1_bo;
    mmAB_f32(wo, wvv, PF[0]);                          // U = wo@wv
    if(t<64){ float s=bo[t]; for(int h=0;h<64;h++) s+=wo[t*64+h]*bv[h];
              VECF[320+cons*128+t]=s; }                 // e = wo@bv + bo
    __syncthreads();
    mmAB_bf(PF[0], q.msg_w, (__bf16*)(ws+(cons?6:4)*8192));  // Nw (direct)
    if(t<64){ float s=0; for(int k=0;k<64;k++) s+=PF[0][t*64+k]*q.msg_b[k];
              VECF[256+cons*128+t]=s; }                 // d = U@msg_b
  }
}

// ---------------- main kernel ----------------
struct Params {
  const float *x, *rnd; const int *idx;
  const float *embed_b, *mean_b, *ls_b;
  const char* ws; float* out; int std_off;
};

__device__ __forceinline__ bf16x8 fragld(const char* buf, int row, int kb){
  const int byte = row*128 + (kb ^ ((row&7)<<4));
  return __builtin_bit_cast(bf16x8, *reinterpret_cast<const uint4v*>(buf + byte));
}
__device__ __forceinline__ bf16x8 gld(const char* a){
  return __builtin_bit_cast(bf16x8, *reinterpret_cast<const uint4v*>(a));
}
__device__ __forceinline__ void stageT(const char* src, char* L, int t){
  __builtin_amdgcn_global_load_lds(
      (const __attribute__((address_space(1))) unsigned int*)(src + t*16),
      (__attribute__((address_space(3))) unsigned int*)(L + (t>>6)*1024), 16, 0, 0);
}
__device__ __forceinline__ void loadB_lds(const char* Bl, bf16x8* bf, int fr, int fg){
  #pragma unroll
  for(int n=0;n<4;n++){
    bf[2*n]   = fragld(Bl, n*16+fr, fg*16);
    bf[2*n+1] = fragld(Bl, n*16+fr, 64+fg*16);
  }
}
__device__ __forceinline__ void loadB_gl(const char* W, bf16x8* bf, int fr, int fg){
  #pragma unroll
  for(int n=0;n<4;n++){
    bf[2*n]   = gld(W + (n*16+fr)*128 + fg*16);
    bf[2*n+1] = gld(W + (n*16+fr)*128 + 64 + fg*16);
  }
}

// acc += A(lds own rows) @ B(lds full tile)
__device__ __forceinline__ void mm_AB(const char* A, const char* Bl, f32x4* acc,
                                      int fr,int fg,int wv4){
  const bf16x8 a0=fragld(A,16*wv4+fr,fg*16), a1=fragld(A,16*wv4+fr,64+fg*16);
  #pragma unroll
  for(int n=0;n<4;n++){
    acc[n]=MFMA16(a0, fragld(Bl,n*16+fr,fg*16),    acc[n]);
    acc[n]=MFMA16(a1, fragld(Bl,n*16+fr,64+fg*16), acc[n]);
  }
}
// acc += A(lds own rows) @ B(preloaded frag regs)
__device__ __forceinline__ void mm_ABr(const char* A, const bf16x8* bf, f32x4* acc,
                                       int fr,int fg,int wv4){
  const bf16x8 a0=fragld(A,16*wv4+fr,fg*16), a1=fragld(A,16*wv4+fr,64+fg*16);
  #pragma unroll
  for(int n=0;n<4;n++){
    acc[n]=MFMA16(a0, bf[2*n],   acc[n]);
    acc[n]=MFMA16(a1, bf[2*n+1], acc[n]);
  }
}
// acc += A(regs 2 frags) @ B(preloaded frag regs)
__device__ __forceinline__ void mm_rAB(bf16x8 a0, bf16x8 a1, const bf16x8* bf,
                                       f32x4* acc){
  #pragma unroll
  for(int n=0;n<4;n++){
    acc[n]=MFMA16(a0, bf[2*n],   acc[n]);
    acc[n]=MFMA16(a1, bf[2*n+1], acc[n]);
  }
}

template<int ACT>
__device__ __forceinline__ void store_cb(char* C, const f32x4* acc, const float* bz,
                                         int fr,int fg,int wv4){
  #pragma unroll
  for(int r=0;r<4;r++){
    const int R=16*wv4+4*fg+r;
    float v[4];
    #pragma unroll
    for(int n=0;n<4;n++) v[n]=actf<ACT>(acc[n][r]+bz[n]);
    uint2 pk; pk.x=pack2(v[0],v[1]); pk.y=pack2(v[2],v[3]);
    *reinterpret_cast<uint2*>(C + R*128 + ((8*fr)^((R&7)<<4))) = pk;
  }
}
__device__ __forceinline__ void store_rb(char* C, const f32x4* acc, const float* dR,
                                         int fr,int fg,int wv4){
  #pragma unroll
  for(int r=0;r<4;r++){
    const int R=16*wv4+4*fg+r;
    float v[4];
    #pragma unroll
    for(int n=0;n<4;n++) v[n]=acc[n][r]+dR[r];
    uint2 pk; pk.x=pack2(v[0],v[1]); pk.y=pack2(v[2],v[3]);
    *reinterpret_cast<uint2*>(C + R*128 + ((8*fr)^((R&7)<<4))) = pk;
  }
}

// Softmax with PRELOADED B-frags, NO max-subtraction (|s*SCALE| bounded ~8;
// exp safe in f32; ratio-identical). MODE 0 plain, 1 mg, 2 1-mg.
template<int MODE>
__device__ __forceinline__ void ssoft(const char* Aq, const bf16x8* bf, char* P,
                                      const float* rs, const float* as_,
                                      const float* zu, const float* zq,
                                      float cu, float cq,
                                      int fr,int fg,int wv4){
  f32x4 acc[4];
  #pragma unroll
  for(int n=0;n<4;n++) acc[n]=f32x4{0.f,0.f,0.f,0.f};
  const bf16x8 a0=fragld(Aq,16*wv4+fr,fg*16), a1=fragld(Aq,16*wv4+fr,64+fg*16);
  #pragma unroll
  for(int n=0;n<4;n++){
    acc[n]=MFMA16(a0, bf[2*n],   acc[n]);
    acc[n]=MFMA16(a1, bf[2*n+1], acc[n]);
  }
  unsigned mbits=0;
  if constexpr(MODE!=0){
    float rc[4], aR[4], ucR[4], qtR[4]; bool giR[4];
    #pragma unroll
    for(int n=0;n<4;n++) rc[n]=rs[n*16+fr];
    #pragma unroll
    for(int r=0;r<4;r++){
      const int R=16*wv4+4*fg+r;
      aR[r]=as_[R]; giR[r]=rs[R]>aR[r];
      ucR[r]=zu[R]+cu; qtR[r]=zq[R]+cq;
    }
    #pragma unroll
    for(int n=0;n<4;n++){
      #pragma unroll
      for(int r=0;r<4;r++){
        bool mv=giR[r]||(rc[n]>aR[r]);
        if constexpr(MODE==2) mv=!mv;
        const float mf=mv?1.f:0.f;
        if(mv) mbits|=1u<<(n*4+r);
        acc[n][r]=(mf*(acc[n][r]+ucR[r])+qtR[r])*SCALE;
      }
    }
  }
  float sm[4]={0,0,0,0};
  #pragma unroll
  for(int n=0;n<4;n++){
    #pragma unroll
    for(int r=0;r<4;r++){
      float e;
      if constexpr(MODE==0) e=__expf(acc[n][r]*SCALE);
      else e=__expf(acc[n][r]);
      acc[n][r]=e; sm[r]+=e;
    }
  }
  #pragma unroll
  for(int m=1;m<16;m<<=1){
    #pragma unroll
    for(int r=0;r<4;r++) sm[r]+=__shfl_xor(sm[r],m);
  }
  #pragma unroll
  for(int r=0;r<4;r++){
    const int R=16*wv4+4*fg+r;
    const float ri=1.f/sm[r];
    float v[4];
    #pragma unroll
    for(int n=0;n<4;n++){
      float e=acc[n][r]*ri;
      if constexpr(MODE!=0) e=(mbits&(1u<<(n*4+r)))?e:0.f;
      v[n]=e;
    }
    uint2 pk; pk.x=pack2(v[0],v[1]); pk.y=pack2(v[2],v[3]);
    *reinterpret_cast<uint2*>(P + R*128 + ((8*fr)^((R&7)<<4))) = pk;
  }
}

__global__ __launch_bounds__(512,4) void rap_kernel(Params p, int Bb){
  __shared__ __align__(16) char Bact[2][3][8192];   // per-item tiles (A2 doubles as
                                                    // embed/M0 staging pre-S4)
  __shared__ float rnd_s[2][64], a_s[2][64], zbuf[2][4][64];
  const int t=threadIdx.x;
  const int fr=t&15, fg=(t>>4)&3, wv=t>>6, l=t&63;
  const int item=wv>>2, wv4=wv&3;
  const int b0=blockIdx.x*2;
  const int bi=(b0+item<Bb)?(b0+item):(Bb-1);
  const char* ws=p.ws;
  const float* VECF=(const float*)(ws+WS_VEC);
  const float* SCF =(const float*)(ws+WS_SC);
  char* A0=Bact[item][0]; char* A1=Bact[item][1]; char* A2=Bact[item][2];
  bf16x8 bfv[8];

  // stage embed -> Bact[0][2], M0 -> Bact[1][2] (A2 tiles free until S4)
  stageT(ws+0*8192, Bact[0][2], t);
  stageT(ws+1*8192, Bact[1][2], t);
  if(t<128){
    const int it2=t>>6, i2=t&63;
    const int bb=(b0+it2<Bb)?(b0+it2):(Bb-1);
    rnd_s[it2][i2]=p.rnd[bb*64+i2];
    a_s[it2][i2]  =p.rnd[bb*64+p.idx[bb*64+i2]];
  }
  // stage x (own 16 rows) -> A0, pi+XOR packed, b128 stores
  {
    const float* Gx=p.x+(size_t)bi*4096;
    #pragma unroll
    for(int j=0;j<2;j++){
      const int lf=j*64+l, R=16*wv4+(lf>>3), k=lf&7;
      const float2 L0=*reinterpret_cast<const float2*>(Gx+R*64+2*k);
      const float2 L1=*reinterpret_cast<const float2*>(Gx+R*64+16+2*k);
      const float2 L2=*reinterpret_cast<const float2*>(Gx+R*64+32+2*k);
      const float2 L3=*reinterpret_cast<const float2*>(Gx+R*64+48+2*k);
      uint4 pk;
      pk.x=pack2(L0.x,L1.x); pk.y=pack2(L2.x,L3.x);
      pk.z=pack2(L0.y,L1.y); pk.w=pack2(L2.y,L3.y);
      *reinterpret_cast<uint4*>(A0 + R*128 + ((16*k)^((R&7)<<4)))=pk;
    }
  }
  bar_full();                                        // BAR_A: x + embed/M0 stageT
  // S1: E = lrelu(x@embed^T + eb) -> A1 (own rows); B = staged embed
  { f32x4 acc[4]={{0,0,0,0},{0,0,0,0},{0,0,0,0},{0,0,0,0}};
    mm_AB(A0, Bact[0][2], acc, fr,fg,wv4);
    float bz[4];
    #pragma unroll
    for(int n=0;n<4;n++) bz[n]=p.embed_b[n*16+fr];
    store_cb<1>(A1, acc, bz, fr,fg,wv4); }
  // S2: T0' = E@M0 + m0 -> A0 (own rows); B = staged M0
  { f32x4 acc[4]={{0,0,0,0},{0,0,0,0},{0,0,0,0},{0,0,0,0}};
    mm_AB(A1, Bact[1][2], acc, fr,fg,wv4);
    float bz[4];
    #pragma unroll
    for(int n=0;n<4;n++) bz[n]=VECF[n*16+fr];
    store_cb<0>(A0, acc, bz, fr,fg,wv4); }
  bar_lgkm();                                        // BAR1: E/T0' full; embed/M0 dead
  // prefetch Wvo A-frags
  const bf16x8 aVo0=gld(ws+2*8192+(16*wv4+fr)*128+fg*16);
  const bf16x8 aVo1=gld(ws+2*8192+(16*wv4+fr)*128+64+fg*16);
  // S3+S4 share B = E (A1)
  loadB_lds(A1, bfv, fr, fg);
  ssoft<0>(A0, bfv, A0, nullptr,nullptr,nullptr,nullptr,0.f,0.f, fr,fg,wv4);
  { f32x4 acc[4]={{0,0,0,0},{0,0,0,0},{0,0,0,0},{0,0,0,0}};
    mm_rAB(aVo0, aVo1, bfv, acc);
    const float bz[4]={0,0,0,0};
    store_cb<0>(A2, acc, bz, fr,fg,wv4); }           // VOT -> A2
  bar_lgkm();                                        // BAR2: VOT full (E dead)
  // prefetch Nv frags
  const bf16x8 nv0=gld(ws+WS_NV+fr*128+fg*16);
  const bf16x8 nv1=gld(ws+WS_NV+fr*128+64+fg*16);
  // S5: ATT = tanh(P@VOT + cc) -> A1 (own rows)
  { f32x4 acc[4]={{0,0,0,0},{0,0,0,0},{0,0,0,0},{0,0,0,0}};
    mm_AB(A0, A2, acc, fr,fg,wv4);
    float bz[4];
    #pragma unroll
    for(int n=0;n<4;n++) bz[n]=VECF[64+n*16+fr];
    store_cb<2>(A1, acc, bz, fr,fg,wv4); }
  // S6: T1' = ATT@M1 + wt1 -> A0 ; Z = ATT@Nv -> zbuf (own rows; M1 JIT)
  { loadB_gl(ws+3*8192, bfv, fr, fg);                // M1 at use site
    const bf16x8 a0=fragld(A1,16*wv4+fr,fg*16), a1=fragld(A1,16*wv4+fr,64+fg*16);
    f32x4 acc[4]={{0,0,0,0},{0,0,0,0},{0,0,0,0},{0,0,0,0}};
    #pragma unroll
    for(int n=0;n<4;n++){
      acc[n]=MFMA16(a0, bfv[2*n],   acc[n]);
      acc[n]=MFMA16(a1, bfv[2*n+1], acc[n]);
    }
    f32x4 za={0,0,0,0};
    za=MFMA16(a0, nv0, za);
    za=MFMA16(a1, nv1, za);
    if(fr<4){
      #pragma unroll
      for(int r=0;r<4;r++) zbuf[item][fr][16*wv4+4*fg+r]=za[r];
    }
    float bz[4];
    #pragma unroll
    for(int n=0;n<4;n++) bz[n]=VECF[128+n*16+fr];
    store_cb<0>(A0, acc, bz, fr,fg,wv4); }
  bar_lgkm();                                        // BAR3: ATT + T1' + zbuf full
  // prefetch Nw1 A-frags
  const bf16x8 aN10=gld(ws+4*8192+(16*wv4+fr)*128+fg*16);
  const bf16x8 aN11=gld(ws+4*8192+(16*wv4+fr)*128+64+fg*16);
  // S7+S7b share B = ATT (A1)
  loadB_lds(A1, bfv, fr, fg);
  ssoft<1>(A0, bfv, A0, rnd_s[item], a_s[item], zbuf[item][0], zbuf[item][1],
           SCF[0], SCF[1], fr,fg,wv4);               // P1 -> A0
  { f32x4 acc[4]={{0,0,0,0},{0,0,0,0},{0,0,0,0},{0,0,0,0}};
    mm_rAB(aN10, aN11, bfv, acc);
    float dR[4];
    #pragma unroll
    for(int r=0;r<4;r++) dR[r]=VECF[256+16*wv4+4*fg+r];
    store_rb(A2, acc, dR, fr,fg,wv4); }              // VMO1T (+d1) -> A2
  bar_lgkm();                                        // BAR4: VMO1T + P1 full
  // prefetch head frags 0-63
  const bf16x8 h0=gld(ws+WS_HW + fr*256 + 0*64 + fg*16);
  const bf16x8 h1=gld(ws+WS_HW + fr*256 + 1*64 + fg*16);
  f32x4 hacc={0,0,0,0};
  // S8a: o1acc = P1@VMO1T; park O1 = lrelu(+e1) -> A0 own rows; fold heads
  { f32x4 o1acc[4]={{0,0,0,0},{0,0,0,0},{0,0,0,0},{0,0,0,0}};
    mm_AB(A0, A2, o1acc, fr,fg,wv4);
    float bz[4];
    #pragma unroll
    for(int n=0;n<4;n++) bz[n]=VECF[320+n*16+fr];
    store_cb<1>(A0, o1acc, bz, fr,fg,wv4); }
  hacc=MFMA16(fragld(A0,16*wv4+fr,fg*16),    h0, hacc);
  hacc=MFMA16(fragld(A0,16*wv4+fr,64+fg*16), h1, hacc);
  // S8b: T2' = ATT@M2 + wt2 -> A0 (own rows; M2 JIT; O1 consumed)
  { loadB_gl(ws+5*8192, bfv, fr, fg);                // M2 at use site
    f32x4 acc[4]={{0,0,0,0},{0,0,0,0},{0,0,0,0},{0,0,0,0}};
    mm_ABr(A1, bfv, acc, fr,fg,wv4);
    float bz[4];
    #pragma unroll
    for(int n=0;n<4;n++) bz[n]=VECF[192+n*16+fr];
    store_cb<0>(A0, acc, bz, fr,fg,wv4); }
  bar_lgkm();                                        // BAR5: A2 reads done; T2' full
  // prefetch Nw2 A-frags; reload ATT B-frags
  const bf16x8 aN20=gld(ws+6*8192+(16*wv4+fr)*128+fg*16);
  const bf16x8 aN21=gld(ws+6*8192+(16*wv4+fr)*128+64+fg*16);
  loadB_lds(A1, bfv, fr, fg);
  // S9: P2 = cons-softmax(T2'@ATT^T, inv) -> A0 ; S9b: VMO2T = Nw2@ATT^T + d2 -> A2
  ssoft<2>(A0, bfv, A0, rnd_s[item], a_s[item], zbuf[item][2], zbuf[item][3],
           SCF[2], SCF[3], fr,fg,wv4);
  { f32x4 acc[4]={{0,0,0,0},{0,0,0,0},{0,0,0,0},{0,0,0,0}};
    mm_rAB(aN20, aN21, bfv, acc);
    float dR[4];
    #pragma unroll
    for(int r=0;r<4;r++) dR[r]=VECF[384+16*wv4+4*fg+r];
    store_rb(A2, acc, dR, fr,fg,wv4); }
  bar_lgkm();                                        // BAR6: VMO2T + P2 full (ATT dead)
  // prefetch head frags 64-127
  const bf16x8 h2=gld(ws+WS_HW + fr*256 + 2*64 + fg*16);
  const bf16x8 h3=gld(ws+WS_HW + fr*256 + 3*64 + fg*16);
  // S10: o2acc = P2@VMO2T; park O2 = lrelu(+e2) -> A1 own rows; fold heads
  { f32x4 acc[4]={{0,0,0,0},{0,0,0,0},{0,0,0,0},{0,0,0,0}};
    mm_AB(A0, A2, acc, fr,fg,wv4);
    float bz[4];
    #pragma unroll
    for(int n=0;n<4;n++) bz[n]=VECF[448+n*16+fr];
    store_cb<1>(A1, acc, bz, fr,fg,wv4); }
  hacc=MFMA16(fragld(A1,16*wv4+fr,fg*16),    h2, hacc);
  hacc=MFMA16(fragld(A1,16*wv4+fr,64+fg*16), h3, hacc);
  // out: row R = agent (own), col fr = out-dim
  if(b0+item<Bb){
    const float bz=(fr<8)?p.mean_b[fr]:p.ls_b[fr-8];
    #pragma unroll
    for(int r=0;r<4;r++){
      const int R=16*wv4+4*fg+r;
      const int g=((b0+item)*64+R)*8;
      float v=hacc[r]+bz;
      if(fr<8) p.out[g+fr]=v;
      else{ v=fminf(fmaxf(v,-20.f),2.f); p.out[p.std_off+g+(fr-8)]=__expf(v); }
    }
  }
}

} // namespace

extern "C" void kernel_launch(void* const* d_in, const int* in_sizes, int n_in,
                              void* d_out, int out_size, void* d_ws, size_t ws_size,
                              hipStream_t stream){
  (void)n_in; (void)out_size; (void)ws_size;
  PrepP q;
  q.embed_w=(const float*)d_in[3];
  q.ia_wq=(const float*)d_in[5];  q.ia_bq=(const float*)d_in[6];
  q.ia_wk=(const float*)d_in[7];
  q.ia_wv=(const float*)d_in[9];  q.ia_bv=(const float*)d_in[10];
  q.ia_wo=(const float*)d_in[11]; q.ia_bo=(const float*)d_in[12];
  q.c1_wq=(const float*)d_in[13]; q.c1_bq=(const float*)d_in[14];
  q.c1_wk=(const float*)d_in[15]; q.c1_bk=(const float*)d_in[16];
  q.c1_wv=(const float*)d_in[17]; q.c1_bv=(const float*)d_in[18];
  q.c1_wo=(const float*)d_in[19]; q.c1_bo=(const float*)d_in[20];
  q.c2_wq=(const float*)d_in[21]; q.c2_bq=(const float*)d_in[22];
  q.c2_wk=(const float*)d_in[23]; q.c2_bk=(const float*)d_in[24];
  q.c2_wv=(const float*)d_in[25]; q.c2_bv=(const float*)d_in[26];
  q.c2_wo=(const float*)d_in[27]; q.c2_bo=(const float*)d_in[28];
  q.msg_w=(const float*)d_in[29]; q.msg_b=(const float*)d_in[30];
  q.st_w =(const float*)d_in[31]; q.st_b =(const float*)d_in[32];
  q.mean_w=(const float*)d_in[33]; q.ls_w=(const float*)d_in[35];
  q.ws=(char*)d_ws;
  prep_kernel<<<dim3(7), dim3(256), 0, stream>>>(q);

  Params p;
  p.x  =(const float*)d_in[0];
  p.rnd=(const float*)d_in[1];
  p.idx=(const int*)  d_in[2];
  p.embed_b=(const float*)d_in[4];
  p.mean_b =(const float*)d_in[34];
  p.ls_b   =(const float*)d_in[36];
  p.ws=(const char*)d_ws;
  p.out=(float*)d_out;
  const int Bb=in_sizes[0]/4096;   // x is [B,64,64]
  p.std_off=Bb*64*8;
  const int nb=(Bb+1)/2;
  rap_kernel<<<dim3(nb), dim3(512), 0, stream>>>(p, Bb);
}

// Round 16
// 115.744 us; speedup vs baseline: 1.3719x; 1.1505x over previous
//
#include <hip/hip_runtime.h>

namespace {

typedef __bf16 bf16x8 __attribute__((ext_vector_type(8)));
typedef float f32x4 __attribute__((ext_vector_type(4)));
typedef unsigned int uint4v __attribute__((ext_vector_type(4)));

#define MFMA16(a,b,c) __builtin_amdgcn_mfma_f32_16x16x32_bf16((a),(b),(c),0,0,0)

constexpr float SCALE = 0.125f;   // 1/sqrt(64)

// ---------------- ws layout ----------------
// slots i*8192, i=0..6: 0 embed, 1 M0T, 2 Wvo, 3 M1T, 4 Nw1, 5 M2T, 6 Nw2
// slots 0,1,3,5 (LDS-staged B-operands): pi-packed + XOR-swizzled rows (linear
//   global_load_lds copy yields the swizzled LDS tile). slots 2,4,6 + NV + HW
//   (direct-global reads): pi-packed plain row-major.
constexpr int WS_HW  = 57344;  // head weights [16][128] bf16, 4096 B
constexpr int WS_NV  = 61440;  // Nv tile [16][64] bf16 (rows 0-3 used), 2048 B
constexpr int WS_VEC = 63488;  // f32 vecs: m0,cc,wt1,wt2,d1,e1,d2,e2 (8 x 64)
constexpr int WS_SC  = 65536;  // f32 scalars: c1, hbk1, c2, hbk2

__device__ __forceinline__ int PI(int c){ return 4*(c&15) + (c>>4); }
__device__ __forceinline__ int PINV(int p){ return 16*(p&3) + (p>>2); }

__device__ __forceinline__ unsigned short f2b(float f){
  return __builtin_bit_cast(unsigned short, (__bf16)f);
}
__device__ __forceinline__ unsigned pack2(float a, float b){
  return (unsigned)f2b(a) | ((unsigned)f2b(b)<<16);
}
template<int ACT>  // 0 none, 1 leaky-relu(0.2), 2 tanh
__device__ __forceinline__ float actf(float v){
  if constexpr (ACT==1) return v>0.f ? v : 0.2f*v;
  else if constexpr (ACT==2) return 1.f - 2.f/(__expf(2.f*v)+1.f);
  else return v;
}

// barrier variants: lgkm-only (LDS-producer barriers — does NOT drain hoisted
// global prefetches) vs full (protects global_load_lds staging).
__device__ __forceinline__ void bar_lgkm(){
  asm volatile("s_waitcnt lgkmcnt(0)\n\ts_barrier" ::: "memory");
}
__device__ __forceinline__ void bar_full(){
  asm volatile("s_waitcnt vmcnt(0) lgkmcnt(0)\n\ts_barrier" ::: "memory");
}

// ---------------- prep kernel (proven, unchanged) ----------------
struct PrepP {
  const float *embed_w, *mean_w, *ls_w;
  const float *ia_wq, *ia_bq, *ia_wk, *ia_wv, *ia_wo, *ia_bv, *ia_bo;
  const float *c1_wq, *c1_bq, *c1_wk, *c1_bk, *c1_wv, *c1_bv, *c1_wo, *c1_bo;
  const float *c2_wq, *c2_bq, *c2_wk, *c2_bk, *c2_wv, *c2_bv, *c2_wo, *c2_bo;
  const float *msg_w, *msg_b, *st_w, *st_b;
  char* ws;
};

__device__ void mmAB_f32(const float* A, const float* B, float* O){
  const int t=threadIdx.x, r=t>>2, c0=(t&3)*16;
  float acc[16];
  #pragma unroll
  for(int j=0;j<16;j++) acc[j]=0.f;
  for(int h=0;h<64;h++){
    const float a=A[r*64+h];
    #pragma unroll
    for(int j=0;j<16;j++) acc[j]=fmaf(a,B[h*64+c0+j],acc[j]);
  }
  #pragma unroll
  for(int j=0;j<16;j++) O[r*64+c0+j]=acc[j];
}
// pi only (direct-global tiles)
__device__ void mmAB_bf(const float* A, const float* B, __bf16* D){
  const int t=threadIdx.x, r=t>>2, c0=(t&3)*16;
  float acc[16];
  #pragma unroll
  for(int j=0;j<16;j++) acc[j]=0.f;
  for(int h=0;h<64;h++){
    const float a=A[r*64+h];
    #pragma unroll
    for(int j=0;j<16;j++) acc[j]=fmaf(a,B[h*64+c0+j],acc[j]);
  }
  #pragma unroll
  for(int j=0;j<16;j++) D[r*64+PI(c0+j)]=(__bf16)acc[j];
}
// pi + XOR row swizzle (LDS-staged tiles)
__device__ void mmTA_bfx(const float* A, const float* B, __bf16* D){
  const int t=threadIdx.x, a=t>>2, b0=(t&3)*16;
  float acc[16];
  #pragma unroll
  for(int j=0;j<16;j++) acc[j]=0.f;
  for(int h=0;h<64;h++){
    const float av=A[h*64+a];
    #pragma unroll
    for(int j=0;j<16;j++) acc[j]=fmaf(av,B[h*64+b0+j],acc[j]);
  }
  #pragma unroll
  for(int j=0;j<16;j++) D[a*64 + (PI(b0+j) ^ ((a&7)<<3))]=(__bf16)acc[j];
}

__global__ void prep_kernel(PrepP q){
  __shared__ float PF[2][4096];
  __shared__ float hv[64], gv[64];
  const int job=blockIdx.x, t=threadIdx.x;
  char* ws=q.ws;
  float* VECF=(float*)(ws+WS_VEC);
  float* SCF =(float*)(ws+WS_SC);
  __bf16* NVD=(__bf16*)(ws+WS_NV);

  if(job==0){
    __bf16* emb=(__bf16*)(ws+0*8192);
    #pragma unroll
    for(int i=0;i<16;i++){
      const int idx=t*16+i, o=idx>>6, pp=idx&63;
      emb[idx]=(__bf16)q.embed_w[o*64 + PINV(pp ^ ((o&7)<<3))];
    }
    __bf16* hw=(__bf16*)(ws+WS_HW);
    #pragma unroll
    for(int i=0;i<8;i++){
      const int flat=t*8+i, o=flat>>7, qq=flat&127, half=qq>>6, pp=qq&63;
      const float v=(o<8)?q.mean_w[o*128+half*64+PINV(pp)]
                         :q.ls_w[(o-8)*128+half*64+PINV(pp)];
      hw[flat]=(__bf16)v;
    }
    #pragma unroll
    for(int i=0;i<3;i++){ const int id=t*3+i; if(id<768) NVD[256+id]=(__bf16)0.f; }
  } else if(job==1){
    mmTA_bfx(q.ia_wk, q.ia_wq, (__bf16*)(ws+1*8192));   // M0T (staged)
    if(t<64){ float s=0; for(int h=0;h<64;h++) s+=q.ia_wk[h*64+t]*q.ia_bq[h]; VECF[t]=s; }
  } else if(job==2){
    mmAB_bf(q.ia_wo, q.ia_wv, (__bf16*)(ws+2*8192));    // Wvo (direct)
    if(t<64){ float s=q.ia_bo[t]; for(int h=0;h<64;h++) s+=q.ia_wo[t*64+h]*q.ia_bv[h];
              VECF[64+t]=s; }
  } else if(job==3 || job==5){
    const int cons=(job==3)?0:1;
    const float *wq=cons?q.c2_wq:q.c1_wq, *bq=cons?q.c2_bq:q.c1_bq;
    const float *wk=cons?q.c2_wk:q.c1_wk, *bk=cons?q.c2_bk:q.c1_bk;
    mmAB_f32(wq, q.st_w, PF[0]);                       // G = wq@st_w
    if(t<64){ float s=bq[t]; for(int k=0;k<64;k++) s+=wq[t*64+k]*q.st_b[k]; hv[t]=s; }
    __syncthreads();
    mmAB_f32(wk, q.msg_w, PF[1]);                      // F = wk@msg_w
    if(t<64){ float s=0; for(int k=0;k<64;k++) s+=wk[t*64+k]*q.msg_b[k]; gv[t]=s; }
    __syncthreads();
    mmTA_bfx(PF[1], PF[0], (__bf16*)(ws+(cons?5:3)*8192));  // M1T/M2T (staged)
    if(t<64){
      float s=0; for(int h=0;h<64;h++) s+=PF[1][h*64+t]*hv[h];
      VECF[128+cons*64+t]=s;                            // wt = F^T h
      float s0=0,s1=0;
      for(int h=0;h<64;h++){ s0+=PF[0][h*64+t]*gv[h]; s1+=PF[0][h*64+t]*bk[h]; }
      NVD[(2*cons  )*64+PI(t)]=(__bf16)s0;              // u-vec  = G^T g
      NVD[(2*cons+1)*64+PI(t)]=(__bf16)s1;              // qb-vec = G^T bk
    }
    if(t==0){
      float c=0,hb=0;
      for(int i=0;i<64;i++){ c+=hv[i]*gv[i]; hb+=hv[i]*bk[i]; }
      SCF[2*cons]=c; SCF[2*cons+1]=hb;
    }
  } else {
    const int cons=(job==4)?0:1;
    const float *wo=cons?q.c2_wo:q.c1_wo, *wvv=cons?q.c2_wv:q.c1_wv;
    const float *bv=cons?q.c2_bv:q.c1_bv, *bo=cons?q.c2_bo:q.c1_bo;
    mmAB_f32(wo, wvv, PF[0]);                          // U = wo@wv
    if(t<64){ float s=bo[t]; for(int h=0;h<64;h++) s+=wo[t*64+h]*bv[h];
              VECF[320+cons*128+t]=s; }                 // e = wo@bv + bo
    __syncthreads();
    mmAB_bf(PF[0], q.msg_w, (__bf16*)(ws+(cons?6:4)*8192));  // Nw (direct)
    if(t<64){ float s=0; for(int k=0;k<64;k++) s+=PF[0][t*64+k]*q.msg_b[k];
              VECF[256+cons*128+t]=s; }                 // d = U@msg_b
  }
}

// ---------------- main kernel ----------------
struct Params {
  const float *x, *rnd; const int *idx;
  const float *embed_b, *mean_b, *ls_b;
  const char* ws; float* out; int std_off;
};

__device__ __forceinline__ bf16x8 fragld(const char* buf, int row, int kb){
  const int byte = row*128 + (kb ^ ((row&7)<<4));
  return __builtin_bit_cast(bf16x8, *reinterpret_cast<const uint4v*>(buf + byte));
}
__device__ __forceinline__ bf16x8 gld(const char* a){
  return __builtin_bit_cast(bf16x8, *reinterpret_cast<const uint4v*>(a));
}
__device__ __forceinline__ void stageT(const char* src, char* L, int t){
  __builtin_amdgcn_global_load_lds(
      (const __attribute__((address_space(1))) unsigned int*)(src + t*16),
      (__attribute__((address_space(3))) unsigned int*)(L + (t>>6)*1024), 16, 0, 0);
}
__device__ __forceinline__ void loadB_lds(const char* Bl, bf16x8* bf, int fr, int fg){
  #pragma unroll
  for(int n=0;n<4;n++){
    bf[2*n]   = fragld(Bl, n*16+fr, fg*16);
    bf[2*n+1] = fragld(Bl, n*16+fr, 64+fg*16);
  }
}

// acc += A(lds own rows) @ B(lds full tile)
__device__ __forceinline__ void mm_AB(const char* A, const char* Bl, f32x4* acc,
                                      int fr,int fg,int wv4){
  const bf16x8 a0=fragld(A,16*wv4+fr,fg*16), a1=fragld(A,16*wv4+fr,64+fg*16);
  #pragma unroll
  for(int n=0;n<4;n++){
    acc[n]=MFMA16(a0, fragld(Bl,n*16+fr,fg*16),    acc[n]);
    acc[n]=MFMA16(a1, fragld(Bl,n*16+fr,64+fg*16), acc[n]);
  }
}
// acc += A(regs 2 frags) @ B(preloaded frag regs)
__device__ __forceinline__ void mm_rAB(bf16x8 a0, bf16x8 a1, const bf16x8* bf,
                                       f32x4* acc){
  #pragma unroll
  for(int n=0;n<4;n++){
    acc[n]=MFMA16(a0, bf[2*n],   acc[n]);
    acc[n]=MFMA16(a1, bf[2*n+1], acc[n]);
  }
}

template<int ACT>
__device__ __forceinline__ void store_cb(char* C, const f32x4* acc, const float* bz,
                                         int fr,int fg,int wv4){
  #pragma unroll
  for(int r=0;r<4;r++){
    const int R=16*wv4+4*fg+r;
    float v[4];
    #pragma unroll
    for(int n=0;n<4;n++) v[n]=actf<ACT>(acc[n][r]+bz[n]);
    uint2 pk; pk.x=pack2(v[0],v[1]); pk.y=pack2(v[2],v[3]);
    *reinterpret_cast<uint2*>(C + R*128 + ((8*fr)^((R&7)<<4))) = pk;
  }
}
__device__ __forceinline__ void store_rb(char* C, const f32x4* acc, const float* dR,
                                         int fr,int fg,int wv4){
  #pragma unroll
  for(int r=0;r<4;r++){
    const int R=16*wv4+4*fg+r;
    float v[4];
    #pragma unroll
    for(int n=0;n<4;n++) v[n]=acc[n][r]+dR[r];
    uint2 pk; pk.x=pack2(v[0],v[1]); pk.y=pack2(v[2],v[3]);
    *reinterpret_cast<uint2*>(C + R*128 + ((8*fr)^((R&7)<<4))) = pk;
  }
}

// Softmax with PRELOADED B-frags, NO max-subtraction (|s*SCALE| bounded ~8 in
// this net; exp safe in f32; ratio-identical math).
// MODE 0: P=softmax(S*SCALE). MODE 1/2: consensus, mask mg / 1-mg, P=softmax*mask.
template<int MODE>
__device__ __forceinline__ void ssoft(const char* Aq, const bf16x8* bf, char* P,
                                      const float* rs, const float* as_,
                                      const float* zu, const float* zq,
                                      float cu, float cq,
                                      int fr,int fg,int wv4){
  f32x4 acc[4];
  #pragma unroll
  for(int n=0;n<4;n++) acc[n]=f32x4{0.f,0.f,0.f,0.f};
  const bf16x8 a0=fragld(Aq,16*wv4+fr,fg*16), a1=fragld(Aq,16*wv4+fr,64+fg*16);
  #pragma unroll
  for(int n=0;n<4;n++){
    acc[n]=MFMA16(a0, bf[2*n],   acc[n]);
    acc[n]=MFMA16(a1, bf[2*n+1], acc[n]);
  }
  unsigned mbits=0;
  if constexpr(MODE!=0){
    float rc[4], aR[4], ucR[4], qtR[4]; bool giR[4];
    #pragma unroll
    for(int n=0;n<4;n++) rc[n]=rs[n*16+fr];
    #pragma unroll
    for(int r=0;r<4;r++){
      const int R=16*wv4+4*fg+r;
      aR[r]=as_[R]; giR[r]=rs[R]>aR[r];
      ucR[r]=zu[R]+cu; qtR[r]=zq[R]+cq;
    }
    #pragma unroll
    for(int n=0;n<4;n++){
      #pragma unroll
      for(int r=0;r<4;r++){
        bool mv=giR[r]||(rc[n]>aR[r]);
        if constexpr(MODE==2) mv=!mv;
        const float mf=mv?1.f:0.f;
        if(mv) mbits|=1u<<(n*4+r);
        acc[n][r]=(mf*(acc[n][r]+ucR[r])+qtR[r])*SCALE;
      }
    }
  }
  float sm[4]={0,0,0,0};
  #pragma unroll
  for(int n=0;n<4;n++){
    #pragma unroll
    for(int r=0;r<4;r++){
      float e;
      if constexpr(MODE==0) e=__expf(acc[n][r]*SCALE);
      else e=__expf(acc[n][r]);
      acc[n][r]=e; sm[r]+=e;
    }
  }
  #pragma unroll
  for(int m=1;m<16;m<<=1){
    #pragma unroll
    for(int r=0;r<4;r++) sm[r]+=__shfl_xor(sm[r],m);
  }
  #pragma unroll
  for(int r=0;r<4;r++){
    const int R=16*wv4+4*fg+r;
    const float ri=1.f/sm[r];
    float v[4];
    #pragma unroll
    for(int n=0;n<4;n++){
      float e=acc[n][r]*ri;
      if constexpr(MODE!=0) e=(mbits&(1u<<(n*4+r)))?e:0.f;
      v[n]=e;
    }
    uint2 pk; pk.x=pack2(v[0],v[1]); pk.y=pack2(v[2],v[3]);
    *reinterpret_cast<uint2*>(P + R*128 + ((8*fr)^((R&7)<<4))) = pk;
  }
}

__global__ __launch_bounds__(512,4) void rap_kernel(Params p, int Bb){
  __shared__ __align__(16) char Bact[2][3][8192];   // per-item activation tiles
  __shared__ __align__(16) char WSst[2][8192];      // weight staging / O1 parking
  __shared__ float rnd_s[2][64], a_s[2][64], zbuf[2][4][64];
  const int t=threadIdx.x;
  const int fr=t&15, fg=(t>>4)&3, wv=t>>6, l=t&63;
  const int item=wv>>2, wv4=wv&3;
  const int b0=blockIdx.x*2;
  const int bi=(b0+item<Bb)?(b0+item):(Bb-1);
  const char* ws=p.ws;
  const float* VECF=(const float*)(ws+WS_VEC);
  const float* SCF =(const float*)(ws+WS_SC);
  char* A0=Bact[item][0]; char* A1=Bact[item][1]; char* A2=Bact[item][2];
  char* WO1=WSst[item];
  bf16x8 bfv[8];

  // stage embed -> WSst[0], M0 -> WSst[1]
  stageT(ws+0*8192, WSst[0], t);
  stageT(ws+1*8192, WSst[1], t);
  if(t<128){
    const int it2=t>>6, i2=t&63;
    const int bb=(b0+it2<Bb)?(b0+it2):(Bb-1);
    rnd_s[it2][i2]=p.rnd[bb*64+i2];
    a_s[it2][i2]  =p.rnd[bb*64+p.idx[bb*64+i2]];
  }
  // stage x (own 16 rows) -> A0, pi+XOR packed, b128 stores
  {
    const float* Gx=p.x+(size_t)bi*4096;
    #pragma unroll
    for(int j=0;j<2;j++){
      const int lf=j*64+l, R=16*wv4+(lf>>3), k=lf&7;
      const float2 L0=*reinterpret_cast<const float2*>(Gx+R*64+2*k);
      const float2 L1=*reinterpret_cast<const float2*>(Gx+R*64+16+2*k);
      const float2 L2=*reinterpret_cast<const float2*>(Gx+R*64+32+2*k);
      const float2 L3=*reinterpret_cast<const float2*>(Gx+R*64+48+2*k);
      uint4 pk;
      pk.x=pack2(L0.x,L1.x); pk.y=pack2(L2.x,L3.x);
      pk.z=pack2(L0.y,L1.y); pk.w=pack2(L2.y,L3.y);
      *reinterpret_cast<uint4*>(A0 + R*128 + ((16*k)^((R&7)<<4)))=pk;
    }
  }
  bar_full();                                        // BAR_A: x + embed/M0 stageT
  // S1: E = lrelu(x@embed^T + eb) -> A1 (own rows)
  { f32x4 acc[4]={{0,0,0,0},{0,0,0,0},{0,0,0,0},{0,0,0,0}};
    mm_AB(A0, WSst[0], acc, fr,fg,wv4);
    float bz[4];
    #pragma unroll
    for(int n=0;n<4;n++) bz[n]=p.embed_b[n*16+fr];
    store_cb<1>(A1, acc, bz, fr,fg,wv4); }
  // S2: T0' = E@M0 + m0 -> A0 (own rows)
  { f32x4 acc[4]={{0,0,0,0},{0,0,0,0},{0,0,0,0},{0,0,0,0}};
    mm_AB(A1, WSst[1], acc, fr,fg,wv4);
    float bz[4];
    #pragma unroll
    for(int n=0;n<4;n++) bz[n]=VECF[n*16+fr];
    store_cb<0>(A0, acc, bz, fr,fg,wv4); }
  bar_lgkm();                                        // BAR1: E full; embed/M0 dead
  // stage M1 -> WSst[0], M2 -> WSst[1]; prefetch Wvo A-frags
  stageT(ws+3*8192, WSst[0], t);
  stageT(ws+5*8192, WSst[1], t);
  const bf16x8 aVo0=gld(ws+2*8192+(16*wv4+fr)*128+fg*16);
  const bf16x8 aVo1=gld(ws+2*8192+(16*wv4+fr)*128+64+fg*16);
  // S3+S4 share B = E (A1): one loadB feeds softmax scores AND VOT
  loadB_lds(A1, bfv, fr, fg);
  // S3: P = softmax(T0'@E^T * SCALE) in-place A0
  ssoft<0>(A0, bfv, A0, nullptr,nullptr,nullptr,nullptr,0.f,0.f, fr,fg,wv4);
  // S4: VOT = Wvo@E^T -> A2 (own rows)
  { f32x4 acc[4]={{0,0,0,0},{0,0,0,0},{0,0,0,0},{0,0,0,0}};
    mm_rAB(aVo0, aVo1, bfv, acc);
    const float bz[4]={0,0,0,0};
    store_cb<0>(A2, acc, bz, fr,fg,wv4); }
  bar_full();                                        // BAR2: VOT full (E dead); M1/M2 landed
  // prefetch Nv frags
  const bf16x8 nv0=gld(ws+WS_NV+fr*128+fg*16);
  const bf16x8 nv1=gld(ws+WS_NV+fr*128+64+fg*16);
  // S5: ATT = tanh(P@VOT + cc) -> A1 (own rows)
  { f32x4 acc[4]={{0,0,0,0},{0,0,0,0},{0,0,0,0},{0,0,0,0}};
    mm_AB(A0, A2, acc, fr,fg,wv4);
    float bz[4];
    #pragma unroll
    for(int n=0;n<4;n++) bz[n]=VECF[64+n*16+fr];
    store_cb<2>(A1, acc, bz, fr,fg,wv4); }
  // S6: T1' = ATT@M1 + wt1 -> A0 ; Z = ATT@Nv -> zbuf (own rows)
  { const bf16x8 a0=fragld(A1,16*wv4+fr,fg*16), a1=fragld(A1,16*wv4+fr,64+fg*16);
    f32x4 acc[4]={{0,0,0,0},{0,0,0,0},{0,0,0,0},{0,0,0,0}};
    #pragma unroll
    for(int n=0;n<4;n++){
      acc[n]=MFMA16(a0, fragld(WSst[0],n*16+fr,fg*16),    acc[n]);
      acc[n]=MFMA16(a1, fragld(WSst[0],n*16+fr,64+fg*16), acc[n]);
    }
    f32x4 za={0,0,0,0};
    za=MFMA16(a0, nv0, za);
    za=MFMA16(a1, nv1, za);
    if(fr<4){
      #pragma unroll
      for(int r=0;r<4;r++) zbuf[item][fr][16*wv4+4*fg+r]=za[r];
    }
    float bz[4];
    #pragma unroll
    for(int n=0;n<4;n++) bz[n]=VECF[128+n*16+fr];
    store_cb<0>(A0, acc, bz, fr,fg,wv4); }
  bar_lgkm();                                        // BAR3: ATT + zbuf full
  // prefetch Nw1 A-frags
  const bf16x8 aN10=gld(ws+4*8192+(16*wv4+fr)*128+fg*16);
  const bf16x8 aN11=gld(ws+4*8192+(16*wv4+fr)*128+64+fg*16);
  // S7+S7b share B = ATT (A1)
  loadB_lds(A1, bfv, fr, fg);
  // S7: P1 = cons-softmax(T1'@ATT^T) in-place A0
  ssoft<1>(A0, bfv, A0, rnd_s[item], a_s[item], zbuf[item][0], zbuf[item][1],
           SCF[0], SCF[1], fr,fg,wv4);
  // S7b: VMO1T = Nw1@ATT^T + d1 -> A2
  { f32x4 acc[4]={{0,0,0,0},{0,0,0,0},{0,0,0,0},{0,0,0,0}};
    mm_rAB(aN10, aN11, bfv, acc);
    float dR[4];
    #pragma unroll
    for(int r=0;r<4;r++) dR[r]=VECF[256+16*wv4+4*fg+r];
    store_rb(A2, acc, dR, fr,fg,wv4); }
  bar_lgkm();                                        // BAR4: VMO1T full
  // S8: O1 = P1@VMO1T -> regs ; T2' = ATT@M2 + wt2 -> A0 (own rows)
  f32x4 o1acc[4]={{0,0,0,0},{0,0,0,0},{0,0,0,0},{0,0,0,0}};
  mm_AB(A0, A2, o1acc, fr,fg,wv4);
  { f32x4 acc[4]={{0,0,0,0},{0,0,0,0},{0,0,0,0},{0,0,0,0}};
    const bf16x8 a0=fragld(A1,16*wv4+fr,fg*16), a1=fragld(A1,16*wv4+fr,64+fg*16);
    #pragma unroll
    for(int n=0;n<4;n++){
      acc[n]=MFMA16(a0, fragld(WSst[1],n*16+fr,fg*16),    acc[n]);
      acc[n]=MFMA16(a1, fragld(WSst[1],n*16+fr,64+fg*16), acc[n]);
    }
    float bz[4];
    #pragma unroll
    for(int n=0;n<4;n++) bz[n]=VECF[192+n*16+fr];
    store_cb<0>(A0, acc, bz, fr,fg,wv4); }
  bar_lgkm();                                        // BAR5: VMO1T reads done; M2 dead
  // park O1 = lrelu(o1acc + e1) -> WSst[item] (own rows)
  { float bz[4];
    #pragma unroll
    for(int n=0;n<4;n++) bz[n]=VECF[320+n*16+fr];
    store_cb<1>(WO1, o1acc, bz, fr,fg,wv4); }
  // prefetch Nw2 A-frags
  const bf16x8 aN20=gld(ws+6*8192+(16*wv4+fr)*128+fg*16);
  const bf16x8 aN21=gld(ws+6*8192+(16*wv4+fr)*128+64+fg*16);
  // S9 pair shares B = ATT (A1)
  loadB_lds(A1, bfv, fr, fg);
  // S9: P2 = cons-softmax(T2'@ATT^T, inv) in-place A0 ; VMO2T = Nw2@ATT^T + d2 -> A2
  ssoft<2>(A0, bfv, A0, rnd_s[item], a_s[item], zbuf[item][2], zbuf[item][3],
           SCF[2], SCF[3], fr,fg,wv4);
  { f32x4 acc[4]={{0,0,0,0},{0,0,0,0},{0,0,0,0},{0,0,0,0}};
    mm_rAB(aN20, aN21, bfv, acc);
    float dR[4];
    #pragma unroll
    for(int r=0;r<4;r++) dR[r]=VECF[384+16*wv4+4*fg+r];
    store_rb(A2, acc, dR, fr,fg,wv4); }
  bar_lgkm();                                        // BAR6: VMO2T full (ATT dead)
  // prefetch head frags
  bf16x8 hw[4];
  #pragma unroll
  for(int kt=0;kt<4;kt++) hw[kt]=gld(ws+WS_HW + fr*256 + kt*64 + fg*16);
  // S10: O2 = lrelu(P2@VMO2T + e2) -> A1 (own rows)
  { f32x4 acc[4]={{0,0,0,0},{0,0,0,0},{0,0,0,0},{0,0,0,0}};
    mm_AB(A0, A2, acc, fr,fg,wv4);
    float bz[4];
    #pragma unroll
    for(int n=0;n<4;n++) bz[n]=VECF[448+n*16+fr];
    store_cb<1>(A1, acc, bz, fr,fg,wv4); }
  // S11: heads (own rows of O1=WO1, O2=A1)
  { f32x4 acc={0,0,0,0};
    #pragma unroll
    for(int kt=0;kt<4;kt++){
      const bf16x8 af=fragld(kt<2?WO1:A1, 16*wv4+fr, (kt&1)*64+fg*16);
      acc=MFMA16(af, hw[kt], acc);
    }
    if(b0+item<Bb){
      const float bz=(fr<8)?p.mean_b[fr]:p.ls_b[fr-8];
      #pragma unroll
      for(int r=0;r<4;r++){
        const int R=16*wv4+4*fg+r;
        const int g=((b0+item)*64+R)*8;
        float v=acc[r]+bz;
        if(fr<8) p.out[g+fr]=v;
        else{ v=fminf(fmaxf(v,-20.f),2.f); p.out[p.std_off+g+(fr-8)]=__expf(v); }
      }
    }
  }
}

} // namespace

extern "C" void kernel_launch(void* const* d_in, const int* in_sizes, int n_in,
                              void* d_out, int out_size, void* d_ws, size_t ws_size,
                              hipStream_t stream){
  (void)n_in; (void)out_size; (void)ws_size;
  PrepP q;
  q.embed_w=(const float*)d_in[3];
  q.ia_wq=(const float*)d_in[5];  q.ia_bq=(const float*)d_in[6];
  q.ia_wk=(const float*)d_in[7];
  q.ia_wv=(const float*)d_in[9];  q.ia_bv=(const float*)d_in[10];
  q.ia_wo=(const float*)d_in[11]; q.ia_bo=(const float*)d_in[12];
  q.c1_wq=(const float*)d_in[13]; q.c1_bq=(const float*)d_in[14];
  q.c1_wk=(const float*)d_in[15]; q.c1_bk=(const float*)d_in[16];
  q.c1_wv=(const float*)d_in[17]; q.c1_bv=(const float*)d_in[18];
  q.c1_wo=(const float*)d_in[19]; q.c1_bo=(const float*)d_in[20];
  q.c2_wq=(const float*)d_in[21]; q.c2_bq=(const float*)d_in[22];
  q.c2_wk=(const float*)d_in[23]; q.c2_bk=(const float*)d_in[24];
  q.c2_wv=(const float*)d_in[25]; q.c2_bv=(const float*)d_in[26];
  q.c2_wo=(const float*)d_in[27]; q.c2_bo=(const float*)d_in[28];
  q.msg_w=(const float*)d_in[29]; q.msg_b=(const float*)d_in[30];
  q.st_w =(const float*)d_in[31]; q.st_b =(const float*)d_in[32];
  q.mean_w=(const float*)d_in[33]; q.ls_w=(const float*)d_in[35];
  q.ws=(char*)d_ws;
  prep_kernel<<<dim3(7), dim3(256), 0, stream>>>(q);

  Params p;
  p.x  =(const float*)d_in[0];
  p.rnd=(const float*)d_in[1];
  p.idx=(const int*)  d_in[2];
  p.embed_b=(const float*)d_in[4];
  p.mean_b =(const float*)d_in[34];
  p.ls_b   =(const float*)d_in[36];
  p.ws=(const char*)d_ws;
  p.out=(float*)d_out;
  const int Bb=in_sizes[0]/4096;   // x is [B,64,64]
  p.std_off=Bb*64*8;
  const int nb=(Bb+1)/2;
  rap_kernel<<<dim3(nb), dim3(512), 0, stream>>>(p, Bb);
}